// Round 1
// baseline (1266.698 us; speedup 1.0000x reference)
//
#include <hip/hip_runtime.h>
#include <stdint.h>

// Problem shape (fixed by setup_inputs): B=32, H=384, W=1280, N=H*W, S=256
#define H_   384
#define W_   1280
#define NPTS (H_ * W_)       // 491520
#define S_   256
#define G_   (S_ * S_)       // 65536 cells per batch
#define NB   16              // histogram blocks per batch

// ---------- helpers ----------
__device__ __forceinline__ unsigned int fkey(float f) {
    unsigned int u = __float_as_uint(f);
    return (u & 0x80000000u) ? ~u : (u | 0x80000000u);  // monotone order-preserving key
}
__device__ __forceinline__ float keyfloat(unsigned int k) {
    unsigned int u = (k & 0x80000000u) ? (k ^ 0x80000000u) : ~k;
    return __uint_as_float(u);
}

// ---------- ground-mask storage-mode detection (byte vs 4-byte word) ----------
__global__ void k_detect(const unsigned int* __restrict__ gm, unsigned int* __restrict__ flag) {
    if (threadIdx.x == 0 && blockIdx.x == 0) {
        unsigned int ok = 1u;
        for (int i = 0; i < 64; i++) {
            unsigned int v = gm[i];
            if (!(v == 0u || v == 1u || v == 0x3F800000u)) { ok = 0u; break; }
        }
        *flag = ok;  // 1: 4-byte elements (int32/float32 bool), 0: 1-byte elements
    }
}

// ---------- quantile radix-select: pass 1, bits [31:20] ----------
__global__ void k_hist1(const float* __restrict__ ptc, unsigned int* __restrict__ h1) {
    __shared__ unsigned int h[4096];
    const int b = blockIdx.y, blk = blockIdx.x;
    for (int j = threadIdx.x; j < 4096; j += blockDim.x) h[j] = 0u;
    __syncthreads();
    const float4* y4 = (const float4*)(ptc + (size_t)b * 3 * NPTS + NPTS);
    const int n4 = NPTS / 4;
    for (int i = blk * blockDim.x + threadIdx.x; i < n4; i += NB * blockDim.x) {
        float4 v = y4[i];
        atomicAdd(&h[fkey(v.x) >> 20], 1u);
        atomicAdd(&h[fkey(v.y) >> 20], 1u);
        atomicAdd(&h[fkey(v.z) >> 20], 1u);
        atomicAdd(&h[fkey(v.w) >> 20], 1u);
    }
    __syncthreads();
    unsigned int* dst = h1 + ((size_t)b * NB + blk) * 4096;
    for (int j = threadIdx.x; j < 4096; j += blockDim.x) dst[j] = h[j];
}

// ctrl layout per batch (8 ints): [0]=c1a [1]=r2a [2]=c1b [3]=r2b [4]=c2a [5]=r3a [6]=c2b [7]=r3b
__global__ void k_select1(const unsigned int* __restrict__ h1, int* __restrict__ ctrl, int ka) {
    const int b = blockIdx.x;
    __shared__ unsigned int h[4096];
    for (int j = threadIdx.x; j < 4096; j += blockDim.x) {
        unsigned int s = 0;
        for (int k = 0; k < NB; k++) s += h1[((size_t)b * NB + k) * 4096 + j];
        h[j] = s;
    }
    __syncthreads();
    if (threadIdx.x == 0) {
        long long ra = ka, rb = (long long)ka + 1, cum = 0;
        int c1a = -1, c1b = -1, r2a = 0, r2b = 0;
        for (int j = 0; j < 4096; j++) {
            long long nc = cum + (long long)h[j];
            if (c1a < 0 && ra < nc) { c1a = j; r2a = (int)(ra - cum); }
            if (c1b < 0 && rb < nc) { c1b = j; r2b = (int)(rb - cum); }
            cum = nc;
            if (c1b >= 0) break;  // ra<rb so c1a is set by now too
        }
        int* c = ctrl + b * 8;
        c[0] = c1a; c[1] = r2a; c[2] = c1b; c[3] = r2b;
    }
}

// pass 2, bits [19:8] within candidate top-12 bin(s)
__global__ void k_hist2(const float* __restrict__ ptc, const int* __restrict__ ctrl,
                        unsigned int* __restrict__ h2) {
    const int b = blockIdx.y;
    const unsigned int c1a = (unsigned int)ctrl[b * 8 + 0];
    const unsigned int c1b = (unsigned int)ctrl[b * 8 + 2];
    unsigned int* ha = h2 + (size_t)b * 2 * 4096;
    unsigned int* hb = ha + 4096;
    const float4* y4 = (const float4*)(ptc + (size_t)b * 3 * NPTS + NPTS);
    const int n4 = NPTS / 4;
    for (int i = blockIdx.x * blockDim.x + threadIdx.x; i < n4; i += NB * blockDim.x) {
        float4 v = y4[i];
        float f[4] = {v.x, v.y, v.z, v.w};
#pragma unroll
        for (int t = 0; t < 4; t++) {
            unsigned int k = fkey(f[t]);
            unsigned int top = k >> 20;
            unsigned int sub = (k >> 8) & 0xFFFu;
            if (top == c1a) atomicAdd(&ha[sub], 1u);
            if (top == c1b) atomicAdd(&hb[sub], 1u);
        }
    }
}

__global__ void k_select2(const unsigned int* __restrict__ h2, int* __restrict__ ctrl) {
    const int b = blockIdx.x;
    if (threadIdx.x != 0) return;
    for (int s = 0; s < 2; s++) {
        const unsigned int* h = h2 + (size_t)b * 2 * 4096 + (size_t)s * 4096;
        long long r = ctrl[b * 8 + 1 + s * 2];
        long long cum = 0; int c2 = 0, r3 = 0;
        for (int j = 0; j < 4096; j++) {
            long long nc = cum + (long long)h[j];
            if (r < nc) { c2 = j; r3 = (int)(r - cum); break; }
            cum = nc;
        }
        ctrl[b * 8 + 4 + s * 2] = c2;
        ctrl[b * 8 + 5 + s * 2] = r3;
    }
}

// pass 3, bits [7:0] within candidate top-24 prefix(es)
__global__ void k_hist3(const float* __restrict__ ptc, const int* __restrict__ ctrl,
                        unsigned int* __restrict__ h3) {
    const int b = blockIdx.y;
    const unsigned int t20a = (((unsigned int)ctrl[b * 8 + 0]) << 12) | (unsigned int)ctrl[b * 8 + 4];
    const unsigned int t20b = (((unsigned int)ctrl[b * 8 + 2]) << 12) | (unsigned int)ctrl[b * 8 + 6];
    unsigned int* ha = h3 + (size_t)b * 2 * 256;
    unsigned int* hb = ha + 256;
    const float4* y4 = (const float4*)(ptc + (size_t)b * 3 * NPTS + NPTS);
    const int n4 = NPTS / 4;
    for (int i = blockIdx.x * blockDim.x + threadIdx.x; i < n4; i += NB * blockDim.x) {
        float4 v = y4[i];
        float f[4] = {v.x, v.y, v.z, v.w};
#pragma unroll
        for (int t = 0; t < 4; t++) {
            unsigned int k = fkey(f[t]);
            unsigned int top = k >> 8;
            if (top == t20a) atomicAdd(&ha[k & 0xFFu], 1u);
            if (top == t20b) atomicAdd(&hb[k & 0xFFu], 1u);
        }
    }
}

// reconstruct order statistics, emulate JAX f32 linear interpolation exactly
__global__ void k_select3(const unsigned int* __restrict__ h3, const int* __restrict__ ctrl,
                          float* __restrict__ tbuf, int nb, float wlo, float whi) {
    const int b = blockIdx.x * blockDim.x + threadIdx.x;
    if (b >= nb) return;
    unsigned int keyv[2];
    for (int s = 0; s < 2; s++) {
        const unsigned int* h = h3 + (size_t)b * 2 * 256 + (size_t)s * 256;
        long long r = ctrl[b * 8 + 5 + s * 2];
        long long cum = 0; int c3 = 0;
        for (int j = 0; j < 256; j++) {
            long long nc = cum + (long long)h[j];
            if (r < nc) { c3 = j; break; }
            cum = nc;
        }
        unsigned int c1 = (unsigned int)ctrl[b * 8 + 0 + s * 2];
        unsigned int c2 = (unsigned int)ctrl[b * 8 + 4 + s * 2];
        keyv[s] = (c1 << 20) | (c2 << 8) | (unsigned int)c3;
    }
    float ylo = keyfloat(keyv[0]);   // y_(k)
    float yhi = keyfloat(keyv[1]);   // y_(k+1)
    // t = ylo*0.71875f + yhi*0.28125f, separate f32 mul/add (no FMA contraction)
    tbuf[b] = __fadd_rn(__fmul_rn(ylo, wlo), __fmul_rn(yhi, whi));
}

// ---------- point scatter ----------
__global__ void k_scatter(const float* __restrict__ depth, const float* __restrict__ ptc,
                          const unsigned char* __restrict__ gmb, const float* __restrict__ tbuf,
                          const unsigned int* __restrict__ mode,
                          unsigned long long* __restrict__ pos_pack,
                          unsigned long long* __restrict__ neg_pack,
                          unsigned int* __restrict__ gcnt) {
    const int b = blockIdx.y;
    const int i = blockIdx.x * blockDim.x + threadIdx.x;
    if (i >= NPTS) return;
    const size_t pb = (size_t)b * 3 * NPTS;
    const float t = tbuf[b];
    const float y = ptc[pb + NPTS + i];
    if (!(y < t)) return;                     // height_mask
    const float x = ptc[pb + i];
    const float z = ptc[pb + 2 * NPTS + i];
    if (!(x >= 0.0f && x <= 255.0f && z >= 0.0f && z <= 255.0f)) return;  // range_mask
    const int xi = (int)x;                    // trunc == floor for x>=0, already in [0,255]
    const int zi = (int)z;
    const size_t cell = (size_t)b * G_ + (size_t)(xi + S_ * zi);

    unsigned int g;
    if (*mode) g = ((const unsigned int*)gmb)[(size_t)b * NPTS + i];
    else       g = (unsigned int)gmb[(size_t)b * NPTS + i];

    if (g) { atomicAdd(&gcnt[cell], 1u); return; }

    // scores: exact f32 replication of assign_score at pixel i
    const int col = i % W_;
    const int r0  = i - col;
    int j1 = col - 2; if (j1 < 0) j1 = 0;
    int j2 = col + 2; if (j2 > W_ - 1) j2 = W_ - 1;
    int am = j1 - 1;  if (am < 0) am = 0;
    int ap = j1 + 1;  if (ap > W_ - 1) ap = W_ - 1;
    int bm = j2 - 1;  if (bm < 0) bm = 0;
    int bp = j2 + 1;  if (bp > W_ - 1) bp = W_ - 1;
    const float* drow = depth + (size_t)b * NPTS + r0;
    float a = drow[ap] - drow[am];
    float c = drow[bp] - drow[bm];
    float rml1 = fmaxf(a, 0.0f),  lmr1 = fmaxf(-a, 0.0f);
    float rml2 = fmaxf(c, 0.0f),  lmr2 = fmaxf(-c, 0.0f);
    float rddx = fmaxf(rml1 - rml2, 0.0f);   // rml_ddx
    float lddx = fmaxf(lmr2 - lmr1, 0.0f);   // lmr_ddx
    float sp, sn;
    if (col < W_ / 2) { sp = rddx; sn = lddx; } else { sp = lddx; sn = rddx; }

    // pack: lo32 = norm (score>0), hi32 = occ (score>0.01)
    if (sp > 0.0f) atomicAdd(&pos_pack[cell], (sp > 0.01f) ? 0x100000001ULL : 1ULL);
    if (sn > 0.0f) atomicAdd(&neg_pack[cell], (sn > 0.01f) ? 0x100000001ULL : 1ULL);
}

// ---------- finalize: pos odds -> out, clipped neg odds -> negbuf ----------
__global__ void k_finalize(const unsigned long long* __restrict__ pos_pack,
                           const unsigned long long* __restrict__ neg_pack,
                           const unsigned int* __restrict__ gcnt,
                           float* __restrict__ out, float* __restrict__ negbuf) {
    const int b = blockIdx.y;
    const int c = blockIdx.x * blockDim.x + threadIdx.x;
    if (c >= G_) return;
    const size_t cell = (size_t)b * G_ + (size_t)c;
    const unsigned long long pp = pos_pack[cell];
    const unsigned int norm_p = (unsigned int)pp;
    const unsigned int occ_p  = (unsigned int)(pp >> 32);
    const float PMAX = 2.1972246f;  // logodds(0.9) in f32; free -> clip(prior) == -PMAX

    float po;
    if (norm_p < 3u) {
        // free = (gcnt>0 && norm==0) -> prior_free -> clip -> p_min; else unknown -> 0
        po = (norm_p == 0u && gcnt[cell] > 0u) ? -PMAX : 0.0f;
    } else {
        float p = (float)occ_p / (float)norm_p;
        float v = logf(p) - log1pf(-p);     // -inf / +inf handled by clamps
        po = fminf(fmaxf(v, -PMAX), PMAX);
    }

    float ng = 0.0f;
    if (norm_p >= 3u) {                      // pos free|unknown  <=>  norm_p<3  -> masked to 0
        const unsigned long long np2 = neg_pack[cell];
        const unsigned int norm_n = (unsigned int)np2;
        if (norm_n >= 3u) {                  // neg free|unknown -> prob 0.5 -> odds 0
            const unsigned int occ_n = (unsigned int)(np2 >> 32);
            float p = (float)occ_n / (float)norm_n;
            float v = logf(p) - log1pf(-p);
            ng = fminf(fmaxf(v, 0.0f), PMAX);
        }
    }
    out[cell] = po;
    negbuf[cell] = ng;
}

// ---------- 3x3 max pool of negbuf, subtract in place ----------
__global__ void k_pool(const float* __restrict__ negbuf, float* __restrict__ out) {
    const int b = blockIdx.y;
    const int c = blockIdx.x * blockDim.x + threadIdx.x;
    if (c >= G_) return;
    const int xi = c & (S_ - 1);
    const int zi = c >> 8;
    const float* nb = negbuf + (size_t)b * G_;
    float m = -INFINITY;
#pragma unroll
    for (int dz = -1; dz <= 1; dz++) {
        int zz = zi + dz; if (zz < 0 || zz >= S_) continue;
#pragma unroll
        for (int dx = -1; dx <= 1; dx++) {
            int xx = xi + dx; if (xx < 0 || xx >= S_) continue;
            m = fmaxf(m, nb[zz * S_ + xx]);
        }
    }
    out[(size_t)b * G_ + (size_t)c] -= m;
}

extern "C" void kernel_launch(void* const* d_in, const int* in_sizes, int n_in,
                              void* d_out, int out_size, void* d_ws, size_t ws_size,
                              hipStream_t stream) {
    const float* depth = (const float*)d_in[0];
    const float* ptc   = (const float*)d_in[1];
    const unsigned char* gm = (const unsigned char*)d_in[2];
    const int B = in_sizes[0] / NPTS;   // 32

    // workspace layout (all 256B aligned); zero region first for single memset
    char* ws = (char*)d_ws;
    size_t off = 0;
    auto alloc = [&](size_t bytes) -> void* {
        void* p = ws + off; off += (bytes + 255) & ~(size_t)255; return p;
    };
    unsigned long long* pos_pack = (unsigned long long*)alloc((size_t)B * G_ * 8);
    unsigned long long* neg_pack = (unsigned long long*)alloc((size_t)B * G_ * 8);
    unsigned int* gcnt = (unsigned int*)alloc((size_t)B * G_ * 4);
    unsigned int* h1   = (unsigned int*)alloc((size_t)B * NB * 4096 * 4);
    unsigned int* h2   = (unsigned int*)alloc((size_t)B * 2 * 4096 * 4);
    unsigned int* h3   = (unsigned int*)alloc((size_t)B * 2 * 256 * 4);
    const size_t zero_bytes = off;
    int* ctrl          = (int*)alloc((size_t)B * 8 * 4);
    float* tbuf        = (float*)alloc((size_t)B * 4);
    unsigned int* mode = (unsigned int*)alloc(4);
    float* negbuf      = (float*)alloc((size_t)B * G_ * 4);
    (void)ws_size;  // requires ~58 MB

    hipMemsetAsync(d_ws, 0, zero_bytes, stream);
    k_detect<<<1, 64, 0, stream>>>((const unsigned int*)gm, mode);

    // rank/weights exactly as JAX f32: index = 0.7f * (N-1) = 344063.28125
    const float idxf = 0.7f * (float)(NPTS - 1);
    const int   ka   = (int)floorf(idxf);
    const float whi  = idxf - (float)ka;     // 0.28125
    const float wlo  = 1.0f - whi;           // 0.71875

    dim3 hblk(256), hgrid(NB, B);
    k_hist1  <<<hgrid, hblk, 0, stream>>>(ptc, h1);
    k_select1<<<dim3(B), dim3(256), 0, stream>>>(h1, ctrl, ka);
    k_hist2  <<<hgrid, hblk, 0, stream>>>(ptc, ctrl, h2);
    k_select2<<<dim3(B), dim3(64), 0, stream>>>(h2, ctrl);
    k_hist3  <<<hgrid, hblk, 0, stream>>>(ptc, ctrl, h3);
    k_select3<<<dim3(1), dim3(64), 0, stream>>>(h3, ctrl, tbuf, B, wlo, whi);

    k_scatter <<<dim3(NPTS / 256, B), dim3(256), 0, stream>>>(
        depth, ptc, gm, tbuf, mode, pos_pack, neg_pack, gcnt);
    k_finalize<<<dim3(G_ / 256, B), dim3(256), 0, stream>>>(
        pos_pack, neg_pack, gcnt, (float*)d_out, negbuf);
    k_pool    <<<dim3(G_ / 256, B), dim3(256), 0, stream>>>(negbuf, (float*)d_out);
}